// Round 3
// baseline (246.538 us; speedup 1.0000x reference)
//
#include <hip/hip_runtime.h>
#include <math.h>

// Problem constants (from reference): N=65536 rows, D=512 features, K=5 centroids.
#define LFR_N 65536
#define LFR_D 512
#define LFR_K 5
#define ROWS   4                         // rows per wave per iteration
#define BLOCKS 1024                      // 4 blocks/CU
#define NWAVES (BLOCKS * 4)              // 4096 waves
#define ITERS  (LFR_N / (NWAVES * ROWS)) // 4 iterations/wave

// R3: persistent-lite streaming kernel.
// R2 post-mortem: cutting VALU 40% (VALUBusy 31->19%) changed dur 81->85us and
// HBM BW was pinned at 2.53 TB/s in both versions => NOT valu- or bw-bound.
// One short-lived row-block per wave (lifetime ~1us, loads in flight ~1/3 of
// life, occupancy avg 34%) is concurrency-limited. Fix: each wave streams 4
// row-blocks; row r of the current block is consumed into dist partials and
// its registers immediately re-issued as the NEXT block's row-r load, so 8
// 16B loads stay in flight under every compute phase. Constants amortized x4.
// nt stores reverted (measured +10MB WRITE, +4us, FETCH unchanged - the L3
// eviction is the harness poison-fill, not our stores).
__global__ __launch_bounds__(256) void lfr_kernel(
    const float* __restrict__ x,        // (N, D)
    const float* __restrict__ alpha,    // (D,)
    const float* __restrict__ w,        // (K, 1)
    const float* __restrict__ cent,     // (K, D)
    float* __restrict__ out_map,        // (N, K)
    float* __restrict__ out_rec,        // (N, D)
    float* __restrict__ out_pred)       // (N,)
{
    const int lane = threadIdx.x & 63;
    const int wib  = threadIdx.x >> 6;
    const int wid  = blockIdx.x * (blockDim.x >> 6) + wib;

    const int d0  = lane * 8;        // this lane's 8 feature indices
    const int hi  = (lane >> 5) & 1; // row bit1 for scatter/gather
    const int mid = (lane >> 4) & 1; // row bit0

    // ---- per-lane constants, loaded ONCE per wave (amortized over ITERS) ----
    float al[8];
    {
        float4 a0 = *(const float4*)(alpha + d0);
        float4 a1 = *(const float4*)(alpha + d0 + 4);
        al[0]=a0.x; al[1]=a0.y; al[2]=a0.z; al[3]=a0.w;
        al[4]=a1.x; al[5]=a1.y; al[6]=a1.z; al[7]=a1.w;
    }
    float c[LFR_K][8];
    #pragma unroll
    for (int k = 0; k < LFR_K; ++k) {
        float4 c0 = *(const float4*)(cent + k * LFR_D + d0);
        float4 c1 = *(const float4*)(cent + k * LFR_D + d0 + 4);
        c[k][0]=c0.x; c[k][1]=c0.y; c[k][2]=c0.z; c[k][3]=c0.w;
        c[k][4]=c1.x; c[k][5]=c1.y; c[k][6]=c1.z; c[k][7]=c1.w;
    }
    float m2a[8];                       // -2*alpha (al dead after cst)
    #pragma unroll
    for (int j = 0; j < 8; ++j) m2a[j] = -2.0f * al[j];
    float cst[LFR_K];                   // lane-partial of sum_d alpha*c_k^2
    #pragma unroll
    for (int k = 0; k < LFR_K; ++k) {
        float s = 0.0f;
        #pragma unroll
        for (int j = 0; j < 8; ++j) {
            float u = al[j] * c[k][j];
            s = fmaf(u, c[k][j], s);
        }
        cst[k] = s;
    }
    float sigw[LFR_K];
    #pragma unroll
    for (int k = 0; k < LFR_K; ++k)
        sigw[k] = 1.0f / (1.0f + __expf(-w[k]));

    // ---- streaming pointers: wave's blocks are strided NWAVES*ROWS rows apart ----
    const size_t XSTEP = (size_t)NWAVES * ROWS * LFR_D;   // elements between blocks
    const float* xp = x + (size_t)wid * ROWS * LFR_D + d0;

    // prologue: load block 0 (8 x 16B loads in flight)
    float4 xl[ROWS][2];
    #pragma unroll
    for (int r = 0; r < ROWS; ++r) {
        xl[r][0] = *(const float4*)(xp + (size_t)r * LFR_D);
        xl[r][1] = *(const float4*)(xp + (size_t)r * LFR_D + 4);
    }

    for (int it = 0; it < ITERS; ++it) {
        const size_t rbase = (size_t)(it * NWAVES + wid) * ROWS;

        // ---- consume current block into shifted-dist partials; re-issue each
        //      row's registers as the NEXT block's load immediately after use ----
        float p[ROWS][LFR_K];
        #pragma unroll
        for (int r = 0; r < ROWS; ++r) {
            float v[8];
            v[0]=m2a[0]*xl[r][0].x; v[1]=m2a[1]*xl[r][0].y;
            v[2]=m2a[2]*xl[r][0].z; v[3]=m2a[3]*xl[r][0].w;
            v[4]=m2a[4]*xl[r][1].x; v[5]=m2a[5]*xl[r][1].y;
            v[6]=m2a[6]*xl[r][1].z; v[7]=m2a[7]*xl[r][1].w;
            #pragma unroll
            for (int k = 0; k < LFR_K; ++k) {
                float acc = cst[k];
                #pragma unroll
                for (int j = 0; j < 8; ++j) acc = fmaf(c[k][j], v[j], acc);
                p[r][k] = acc;
            }
            if (it + 1 < ITERS) {       // prefetch next block's row r (in flight under shuffles+rec)
                const float* nx = xp + XSTEP + (size_t)r * LFR_D;
                xl[r][0] = *(const float4*)(nx);
                xl[r][1] = *(const float4*)(nx + 4);
            }
        }

        // ---- reduce-scatter: rows -> 16-lane groups (group g owns row rbase+g) ----
        float q[2][LFR_K];
        #pragma unroll
        for (int r2 = 0; r2 < 2; ++r2) {
            #pragma unroll
            for (int k = 0; k < LFR_K; ++k) {
                float send = hi ? p[r2][k]     : p[2 + r2][k];
                float keep = hi ? p[2 + r2][k] : p[r2][k];
                q[r2][k] = keep + __shfl_xor(send, 32);
            }
        }
        float s[LFR_K];
        #pragma unroll
        for (int k = 0; k < LFR_K; ++k) {
            float send = mid ? q[0][k] : q[1][k];
            float keep = mid ? q[1][k] : q[0][k];
            s[k] = keep + __shfl_xor(send, 16);
        }
        #pragma unroll
        for (int off = 8; off > 0; off >>= 1) {
            #pragma unroll
            for (int k = 0; k < LFR_K; ++k)
                s[k] += __shfl_xor(s[k], off);
        }

        // ---- softmax over K, once per lane (row g = lane>>4) ----
        float e[LFR_K];
        {
            float mx = s[0];
            #pragma unroll
            for (int k = 1; k < LFR_K; ++k) mx = fmaxf(mx, s[k]);
            float sum = 0.0f;
            #pragma unroll
            for (int k = 0; k < LFR_K; ++k) { e[k] = __expf(s[k] - mx); sum += e[k]; }
            float inv = 1.0f / sum;
            #pragma unroll
            for (int k = 0; k < LFR_K; ++k) e[k] *= inv;
        }

        // ---- mapping + pred: sublane 0 of each 16-lane group writes its row ----
        if ((lane & 15) == 0) {
            const int g = lane >> 4;
            float* mp = out_map + (rbase + g) * LFR_K;
            *(float4*)(mp) = make_float4(e[0], e[1], e[2], e[3]);
            mp[4] = e[4];
            float pr = e[0] * sigw[0];
            #pragma unroll
            for (int k = 1; k < LFR_K; ++k) pr = fmaf(e[k], sigw[k], pr);
            out_pred[rbase + g] = pr;
        }

        // ---- allgather m back to all lanes (compile-time indices only) ----
        float mA[2][LFR_K];            // rows {2*hi+0, 2*hi+1}
        #pragma unroll
        for (int k = 0; k < LFR_K; ++k) {
            float o = __shfl_xor(e[k], 16);
            mA[0][k] = mid ? o    : e[k];
            mA[1][k] = mid ? e[k] : o;
        }
        float M[ROWS][LFR_K];
        #pragma unroll
        for (int r2 = 0; r2 < 2; ++r2) {
            #pragma unroll
            for (int k = 0; k < LFR_K; ++k) {
                float o = __shfl_xor(mA[r2][k], 32);
                M[r2][k]     = hi ? o         : mA[r2][k];
                M[2 + r2][k] = hi ? mA[r2][k] : o;
            }
        }

        // ---- reconstruction: rec[d] = sum_k M[k] * c[k][d] ----
        #pragma unroll
        for (int r = 0; r < ROWS; ++r) {
            float rv[8];
            #pragma unroll
            for (int j = 0; j < 8; ++j) {
                float acc = M[r][0] * c[0][j];
                #pragma unroll
                for (int k = 1; k < LFR_K; ++k) acc = fmaf(M[r][k], c[k][j], acc);
                rv[j] = acc;
            }
            float* rr = out_rec + (rbase + r) * LFR_D + d0;
            *(float4*)(rr)     = make_float4(rv[0], rv[1], rv[2], rv[3]);
            *(float4*)(rr + 4) = make_float4(rv[4], rv[5], rv[6], rv[7]);
        }

        xp += XSTEP;
    }
}

extern "C" void kernel_launch(void* const* d_in, const int* in_sizes, int n_in,
                              void* d_out, int out_size, void* d_ws, size_t ws_size,
                              hipStream_t stream) {
    const float* x     = (const float*)d_in[0];   // (N, D)
    // d_in[1] = is_protected — unused by the reference computation
    const float* alpha = (const float*)d_in[2];   // (D,)
    const float* w     = (const float*)d_in[3];   // (K, 1)
    const float* cent  = (const float*)d_in[4];   // (K, D)

    float* out   = (float*)d_out;
    float* o_map = out;                                         // N*K
    float* o_rec = out + (size_t)LFR_N * LFR_K;                 // N*D
    float* o_prd = out + (size_t)LFR_N * LFR_K + (size_t)LFR_N * LFR_D;  // N

    // 1024 blocks x 256 threads = 4096 waves, each streaming ITERS=4 blocks of
    // ROWS=4 rows with one-deep in-place prefetch (loads always in flight).
    dim3 grid(BLOCKS), block(256);
    lfr_kernel<<<grid, block, 0, stream>>>(x, alpha, w, cent, o_map, o_rec, o_prd);
}

// Round 4
// 244.880 us; speedup vs baseline: 1.0068x; 1.0068x over previous
//
#include <hip/hip_runtime.h>
#include <math.h>

// Problem constants (from reference): N=65536 rows, D=512 features, K=5 centroids.
#define LFR_N 65536
#define LFR_D 512
#define LFR_K 5
#define ROWS   4                         // rows per wave per iteration
#define BLOCKS 1024                      // 4 blocks/CU
#define NWAVES (BLOCKS * 4)              // 4096 waves
#define ITERS  (LFR_N / (NWAVES * ROWS)) // 4 iterations/wave

// R4: canonical coalescing. R0-R3 post-mortem: three structurally different
// kernels (VALU -50%, shuffles -60%, prefetch streaming) all land at 82-85us
// with HBM pinned at 2.45 TB/s and every visible pipe <35% busy. The ONE
// invariant was the d0=lane*8 layout: every load/store had lane-stride 32B,
// spanning 2KB/instruction with 32 half-covered cache lines. Theory: the
// CU-shared vector-mem address path charges per distinct line -> 2x address
// cost on all ~18 mem insts/wave-iter, serializing all 16 waves/CU on the
// shared TA/L1 path (structure-independent, matches total idleness).
// Fix: lane i owns d = i*4 (half A, bytes [0,1KB)) and d = 256+i*4 (half B,
// bytes [1KB,2KB)) -> every mem inst is a fully-covered contiguous 1KB span.
// Lane->d ownership changes; wave-reduction math identical (lanes still
// partition all 512 d's exactly once).
__global__ __launch_bounds__(256) void lfr_kernel(
    const float* __restrict__ x,        // (N, D)
    const float* __restrict__ alpha,    // (D,)
    const float* __restrict__ w,        // (K, 1)
    const float* __restrict__ cent,     // (K, D)
    float* __restrict__ out_map,        // (N, K)
    float* __restrict__ out_rec,        // (N, D)
    float* __restrict__ out_pred)       // (N,)
{
    const int lane = threadIdx.x & 63;
    const int wib  = threadIdx.x >> 6;
    const int wid  = blockIdx.x * (blockDim.x >> 6) + wib;

    const int dA  = lane * 4;        // this lane's first-half float4 (d = dA..dA+3)
                                     // second half at d = dA+256..dA+259
    const int hi  = (lane >> 5) & 1; // row bit1 for scatter/gather
    const int mid = (lane >> 4) & 1; // row bit0

    // ---- per-lane constants, loaded ONCE per wave (amortized over ITERS) ----
    float al[8];
    {
        float4 a0 = *(const float4*)(alpha + dA);
        float4 a1 = *(const float4*)(alpha + dA + 256);
        al[0]=a0.x; al[1]=a0.y; al[2]=a0.z; al[3]=a0.w;
        al[4]=a1.x; al[5]=a1.y; al[6]=a1.z; al[7]=a1.w;
    }
    float c[LFR_K][8];
    #pragma unroll
    for (int k = 0; k < LFR_K; ++k) {
        float4 c0 = *(const float4*)(cent + k * LFR_D + dA);
        float4 c1 = *(const float4*)(cent + k * LFR_D + dA + 256);
        c[k][0]=c0.x; c[k][1]=c0.y; c[k][2]=c0.z; c[k][3]=c0.w;
        c[k][4]=c1.x; c[k][5]=c1.y; c[k][6]=c1.z; c[k][7]=c1.w;
    }
    float m2a[8];                       // -2*alpha
    #pragma unroll
    for (int j = 0; j < 8; ++j) m2a[j] = -2.0f * al[j];
    float cst[LFR_K];                   // lane-partial of sum_d alpha*c_k^2
    #pragma unroll
    for (int k = 0; k < LFR_K; ++k) {
        float s = 0.0f;
        #pragma unroll
        for (int j = 0; j < 8; ++j) {
            float u = al[j] * c[k][j];
            s = fmaf(u, c[k][j], s);
        }
        cst[k] = s;
    }
    float sigw[LFR_K];
    #pragma unroll
    for (int k = 0; k < LFR_K; ++k)
        sigw[k] = 1.0f / (1.0f + __expf(-w[k]));

    // ---- streaming pointers: wave's blocks are strided NWAVES*ROWS rows apart ----
    const size_t XSTEP = (size_t)NWAVES * ROWS * LFR_D;   // elements between blocks
    const float* xp = x + (size_t)wid * ROWS * LFR_D;     // row base (no lane offset)

    // prologue: load block 0 (8 x 16B loads in flight, each a 1KB wave-span)
    float4 xl[ROWS][2];
    #pragma unroll
    for (int r = 0; r < ROWS; ++r) {
        xl[r][0] = *(const float4*)(xp + (size_t)r * LFR_D + dA);
        xl[r][1] = *(const float4*)(xp + (size_t)r * LFR_D + dA + 256);
    }

    for (int it = 0; it < ITERS; ++it) {
        const size_t rbase = (size_t)(it * NWAVES + wid) * ROWS;

        // ---- consume current block into shifted-dist partials; re-issue each
        //      row's registers as the NEXT block's load immediately after use ----
        float p[ROWS][LFR_K];
        #pragma unroll
        for (int r = 0; r < ROWS; ++r) {
            float v[8];
            v[0]=m2a[0]*xl[r][0].x; v[1]=m2a[1]*xl[r][0].y;
            v[2]=m2a[2]*xl[r][0].z; v[3]=m2a[3]*xl[r][0].w;
            v[4]=m2a[4]*xl[r][1].x; v[5]=m2a[5]*xl[r][1].y;
            v[6]=m2a[6]*xl[r][1].z; v[7]=m2a[7]*xl[r][1].w;
            #pragma unroll
            for (int k = 0; k < LFR_K; ++k) {
                float acc = cst[k];
                #pragma unroll
                for (int j = 0; j < 8; ++j) acc = fmaf(c[k][j], v[j], acc);
                p[r][k] = acc;
            }
            if (it + 1 < ITERS) {       // prefetch next block's row r
                const float* nx = xp + XSTEP + (size_t)r * LFR_D;
                xl[r][0] = *(const float4*)(nx + dA);
                xl[r][1] = *(const float4*)(nx + dA + 256);
            }
        }

        // ---- reduce-scatter: rows -> 16-lane groups (group g owns row rbase+g) ----
        float q[2][LFR_K];
        #pragma unroll
        for (int r2 = 0; r2 < 2; ++r2) {
            #pragma unroll
            for (int k = 0; k < LFR_K; ++k) {
                float send = hi ? p[r2][k]     : p[2 + r2][k];
                float keep = hi ? p[2 + r2][k] : p[r2][k];
                q[r2][k] = keep + __shfl_xor(send, 32);
            }
        }
        float s[LFR_K];
        #pragma unroll
        for (int k = 0; k < LFR_K; ++k) {
            float send = mid ? q[0][k] : q[1][k];
            float keep = mid ? q[1][k] : q[0][k];
            s[k] = keep + __shfl_xor(send, 16);
        }
        #pragma unroll
        for (int off = 8; off > 0; off >>= 1) {
            #pragma unroll
            for (int k = 0; k < LFR_K; ++k)
                s[k] += __shfl_xor(s[k], off);
        }

        // ---- softmax over K, once per lane (row g = lane>>4) ----
        float e[LFR_K];
        {
            float mx = s[0];
            #pragma unroll
            for (int k = 1; k < LFR_K; ++k) mx = fmaxf(mx, s[k]);
            float sum = 0.0f;
            #pragma unroll
            for (int k = 0; k < LFR_K; ++k) { e[k] = __expf(s[k] - mx); sum += e[k]; }
            float inv = 1.0f / sum;
            #pragma unroll
            for (int k = 0; k < LFR_K; ++k) e[k] *= inv;
        }

        // ---- mapping + pred: sublane 0 of each 16-lane group writes its row ----
        if ((lane & 15) == 0) {
            const int g = lane >> 4;
            float* mp = out_map + (rbase + g) * LFR_K;
            *(float4*)(mp) = make_float4(e[0], e[1], e[2], e[3]);
            mp[4] = e[4];
            float pr = e[0] * sigw[0];
            #pragma unroll
            for (int k = 1; k < LFR_K; ++k) pr = fmaf(e[k], sigw[k], pr);
            out_pred[rbase + g] = pr;
        }

        // ---- allgather m back to all lanes (compile-time indices only) ----
        float mA[2][LFR_K];            // rows {2*hi+0, 2*hi+1}
        #pragma unroll
        for (int k = 0; k < LFR_K; ++k) {
            float o = __shfl_xor(e[k], 16);
            mA[0][k] = mid ? o    : e[k];
            mA[1][k] = mid ? e[k] : o;
        }
        float M[ROWS][LFR_K];
        #pragma unroll
        for (int r2 = 0; r2 < 2; ++r2) {
            #pragma unroll
            for (int k = 0; k < LFR_K; ++k) {
                float o = __shfl_xor(mA[r2][k], 32);
                M[r2][k]     = hi ? o         : mA[r2][k];
                M[2 + r2][k] = hi ? mA[r2][k] : o;
            }
        }

        // ---- reconstruction: rec[d] = sum_k M[k] * c[k][d] ----
        #pragma unroll
        for (int r = 0; r < ROWS; ++r) {
            float rv[8];
            #pragma unroll
            for (int j = 0; j < 8; ++j) {
                float acc = M[r][0] * c[0][j];
                #pragma unroll
                for (int k = 1; k < LFR_K; ++k) acc = fmaf(M[r][k], c[k][j], acc);
                rv[j] = acc;
            }
            float* rr = out_rec + (rbase + r) * LFR_D;
            *(float4*)(rr + dA)       = make_float4(rv[0], rv[1], rv[2], rv[3]);
            *(float4*)(rr + dA + 256) = make_float4(rv[4], rv[5], rv[6], rv[7]);
        }

        xp += XSTEP;
    }
}

extern "C" void kernel_launch(void* const* d_in, const int* in_sizes, int n_in,
                              void* d_out, int out_size, void* d_ws, size_t ws_size,
                              hipStream_t stream) {
    const float* x     = (const float*)d_in[0];   // (N, D)
    // d_in[1] = is_protected — unused by the reference computation
    const float* alpha = (const float*)d_in[2];   // (D,)
    const float* w     = (const float*)d_in[3];   // (K, 1)
    const float* cent  = (const float*)d_in[4];   // (K, D)

    float* out   = (float*)d_out;
    float* o_map = out;                                         // N*K
    float* o_rec = out + (size_t)LFR_N * LFR_K;                 // N*D
    float* o_prd = out + (size_t)LFR_N * LFR_K + (size_t)LFR_N * LFR_D;  // N

    // 1024 blocks x 256 threads = 4096 waves, each streaming ITERS=4 blocks of
    // ROWS=4 rows with one-deep in-place prefetch (loads always in flight).
    dim3 grid(BLOCKS), block(256);
    lfr_kernel<<<grid, block, 0, stream>>>(x, alpha, w, cent, o_map, o_rec, o_prd);
}